// Round 1
// baseline (695.054 us; speedup 1.0000x reference)
//
#include <hip/hip_runtime.h>
#include <hip/hip_bf16.h>
#include <stdint.h>

#define N_TOK 32768
#define DDIM  768
#define FDIM  3072
#define NCOLS (2*FDIM)      // 6144 rows of W1cat
#define BK    32
#define KTILES (DDIM/BK)    // 24
#define NTILES (NCOLS/128)  // 48 column tiles

typedef __attribute__((ext_vector_type(8))) short bf16x8;
typedef __attribute__((ext_vector_type(4))) float f32x4;

__device__ __forceinline__ unsigned short f2bf(float f) {
  unsigned u = __builtin_bit_cast(unsigned, f);
  unsigned r = (u + 0x7fffu + ((u >> 16) & 1u)) >> 16;
  return (unsigned short)r;
}

__device__ __forceinline__ void gl_lds16(const void* g, void* l) {
  __builtin_amdgcn_global_load_lds(
      (const __attribute__((address_space(1))) unsigned int*)g,
      (__attribute__((address_space(3))) unsigned int*)l, 16, 0, 0);
}

// ---------- W1[:2] fp32 -> bf16 ----------
__global__ __launch_bounds__(256) void cvt_kernel(const float* __restrict__ src,
                                                  unsigned short* __restrict__ dst) {
  size_t i = ((size_t)blockIdx.x * 256 + threadIdx.x) * 4;
  float4 f = *(const float4*)(src + i);
  ushort4 u;
  u.x = f2bf(f.x); u.y = f2bf(f.y); u.z = f2bf(f.z); u.w = f2bf(f.w);
  *(ushort4*)(dst + i) = u;
}

// ---------- v[k][f] = sum_d W2[k,d,f] * W3[k,0,d] ----------
__global__ __launch_bounds__(256) void vcalc_kernel(const float* __restrict__ W2,
                                                    const float* __restrict__ W3,
                                                    float* __restrict__ v) {
  __shared__ float w3s[DDIM];
  int k  = blockIdx.x / (FDIM/256);
  int fb = blockIdx.x % (FDIM/256);
  for (int d = threadIdx.x; d < DDIM; d += 256) w3s[d] = W3[k*DDIM + d];
  __syncthreads();
  int f = fb*256 + threadIdx.x;
  const float* W2k = W2 + (size_t)k * DDIM * FDIM + f;
  float s = 0.f;
  #pragma unroll 8
  for (int d = 0; d < DDIM; ++d) s += W2k[(size_t)d*FDIM] * w3s[d];
  v[k*FDIM + f] = s;
}

// ---------- c[k] = dot(b2[k], W3[k]) + b3[k] ----------
__global__ __launch_bounds__(256) void ccalc_kernel(const float* __restrict__ b2,
                                                    const float* __restrict__ W3,
                                                    const float* __restrict__ b3,
                                                    float* __restrict__ cbuf) {
  __shared__ float red[256];
  for (int k = 0; k < 2; ++k) {
    float s = 0.f;
    for (int d = threadIdx.x; d < DDIM; d += 256) s += b2[k*DDIM+d] * W3[k*DDIM+d];
    red[threadIdx.x] = s;
    __syncthreads();
    for (int off = 128; off > 0; off >>= 1) {
      if (threadIdx.x < off) red[threadIdx.x] += red[threadIdx.x+off];
      __syncthreads();
    }
    if (threadIdx.x == 0) cbuf[k] = red[0] + b3[k];
    __syncthreads();
  }
}

// ---------- gate (softmax top-2 weights) + x->bf16 + W3 dots, one wave/row ----------
__global__ __launch_bounds__(256) void gate_cvt_kernel(
    const float* __restrict__ x, const float* __restrict__ Wg,
    const float* __restrict__ W3, const float* __restrict__ cbuf,
    unsigned short* __restrict__ xbf,
    float* __restrict__ wgt, float* __restrict__ base) {
  int wid  = threadIdx.x >> 6;
  int lane = threadIdx.x & 63;
  int n = blockIdx.x * 4 + wid;
  const float* xr = x + (size_t)n * DDIM;
  float acc[8] = {0,0,0,0,0,0,0,0};
  float d30 = 0.f, d31 = 0.f;
  #pragma unroll
  for (int it = 0; it < DDIM/64; ++it) {
    int i = it*64 + lane;
    float xv = xr[i];
    xbf[(size_t)n*DDIM + i] = f2bf(xv);
    #pragma unroll
    for (int e = 0; e < 8; ++e) acc[e] += xv * Wg[e*DDIM + i];
    d30 += xv * W3[i];
    d31 += xv * W3[DDIM + i];
  }
  #pragma unroll
  for (int m = 1; m < 64; m <<= 1) {
    #pragma unroll
    for (int e = 0; e < 8; ++e) acc[e] += __shfl_xor(acc[e], m, 64);
    d30 += __shfl_xor(d30, m, 64);
    d31 += __shfl_xor(d31, m, 64);
  }
  if (lane == 0) {
    float l1 = acc[0]; int a1 = 0;
    #pragma unroll
    for (int e = 1; e < 8; ++e) if (acc[e] > l1) { l1 = acc[e]; a1 = e; }
    float l2 = -3.4e38f;
    #pragma unroll
    for (int e = 0; e < 8; ++e) if (e != a1 && acc[e] > l2) l2 = acc[e];
    float w0 = 1.f / (1.f + __expf(l2 - l1));   // top prob / (top + 2nd), softmax Z cancels
    float w1 = 1.f - w0;
    wgt[2*n]   = w0;
    wgt[2*n+1] = w1;
    base[n] = w0 * (d30 + cbuf[0]) + w1 * (d31 + cbuf[1]);
  }
}

// ---------- fused GEMM: part[bn][row] = sum_{col in tile bn} relu(X@W1cat^T + b1)[row][col] * v[col] ----------
__global__ __launch_bounds__(256) void gemm_kernel(
    const unsigned short* __restrict__ A,   // 32768 x 768 bf16
    const unsigned short* __restrict__ B,   // 6144 x 768 bf16 (W1cat, B^T layout)
    const float* __restrict__ b1,           // 6144
    const float* __restrict__ v,            // 6144
    float* __restrict__ part) {             // 48 x 32768
  __shared__ __align__(16) unsigned short As[128*BK];
  __shared__ __align__(16) unsigned short Bs[128*BK];
  __shared__ float red[256];

  const int tid  = threadIdx.x;
  const int lane = tid & 63, wid = tid >> 6;
  const int wr = wid >> 1, wc = wid & 1;
  const int q  = lane >> 4, cl = lane & 15;
  const int bn = blockIdx.x;     // 0..47 col tile
  const int bm = blockIdx.y;     // 0..255 row tile

  // staging: thread t stages 16B slots t and t+256 (linear in LDS = global_load_lds order)
  // XOR swizzle: slot(r,kq) = r*4 + (kq ^ ((r>>1)&3))  -> 2-way bank aliasing (free)
  const int r0  = tid >> 2;
  const int kq0 = (tid & 3) ^ ((r0 >> 1) & 3);
  const int r1  = r0 + 64;
  const int kq1 = (tid & 3) ^ ((r1 >> 1) & 3);

  const unsigned short* Ab = A + (size_t)bm * 128 * DDIM;
  const unsigned short* Bb = B + (size_t)bn * 128 * DDIM;

  f32x4 zero = {0.f, 0.f, 0.f, 0.f};
  f32x4 acc[4][4];
  #pragma unroll
  for (int i = 0; i < 4; ++i)
    #pragma unroll
    for (int j = 0; j < 4; ++j) acc[i][j] = zero;

  // fragment LDS byte offsets: A[m=lane&15][k=q*8+j], B mirrors (B^T rows)
  int aoff[4], boff[4];
  #pragma unroll
  for (int i = 0; i < 4; ++i) {
    int ra = wr*64 + i*16 + cl;
    aoff[i] = (ra*4 + (q ^ ((ra>>1)&3))) * 16;
    int rb = wc*64 + i*16 + cl;
    boff[i] = (rb*4 + (q ^ ((rb>>1)&3))) * 16;
  }
  char* AsB = (char*)As;
  char* BsB = (char*)Bs;

  for (int kt = 0; kt < KTILES; ++kt) {
    int k0 = kt * BK;
    gl_lds16(Ab + (size_t)r0*DDIM + k0 + kq0*8, AsB + wid*1024);
    gl_lds16(Ab + (size_t)r1*DDIM + k0 + kq1*8, AsB + 4096 + wid*1024);
    gl_lds16(Bb + (size_t)r0*DDIM + k0 + kq0*8, BsB + wid*1024);
    gl_lds16(Bb + (size_t)r1*DDIM + k0 + kq1*8, BsB + 4096 + wid*1024);
    __syncthreads();
    bf16x8 af[4], bfr[4];
    #pragma unroll
    for (int i = 0; i < 4; ++i) {
      af[i]  = *(const bf16x8*)(AsB + aoff[i]);
      bfr[i] = *(const bf16x8*)(BsB + boff[i]);
    }
    #pragma unroll
    for (int i = 0; i < 4; ++i)
      #pragma unroll
      for (int j = 0; j < 4; ++j)
        acc[i][j] = __builtin_amdgcn_mfma_f32_16x16x32_bf16(af[i], bfr[j], acc[i][j], 0, 0, 0);
    __syncthreads();
  }

  // epilogue: relu(acc + b1[col]) * v[col], reduce over the tile's 128 cols per row
  float vv[4], bb[4];
  #pragma unroll
  for (int j = 0; j < 4; ++j) {
    int cg = bn*128 + wc*64 + j*16 + cl;
    vv[j] = v[cg];
    bb[j] = b1[cg];
  }
  // C/D layout: row = q*4 + reg, col = lane&15 (within each 16x16 tile)
  #pragma unroll
  for (int i = 0; i < 4; ++i) {
    #pragma unroll
    for (int r = 0; r < 4; ++r) {
      float s = 0.f;
      #pragma unroll
      for (int j = 0; j < 4; ++j) {
        float val = acc[i][j][r] + bb[j];
        val = fmaxf(val, 0.f);
        s += val * vv[j];
      }
      #pragma unroll
      for (int m = 1; m < 16; m <<= 1) s += __shfl_xor(s, m, 64);
      if (cl == 0) red[(wr*64 + i*16 + q*4 + r)*2 + wc] = s;
    }
  }
  __syncthreads();
  if (tid < 128)
    part[(size_t)bn * N_TOK + bm*128 + tid] = red[tid*2] + red[tid*2+1];
}

// ---------- final combine ----------
__global__ __launch_bounds__(256) void final_kernel(const float* __restrict__ part,
                                                    const float* __restrict__ wgt,
                                                    const float* __restrict__ base,
                                                    float* __restrict__ out) {
  int n = blockIdx.x * 256 + threadIdx.x;
  float s0 = 0.f, s1 = 0.f;
  #pragma unroll
  for (int t = 0; t < 24; ++t) s0 += part[(size_t)t*N_TOK + n];
  #pragma unroll
  for (int t = 24; t < 48; ++t) s1 += part[(size_t)t*N_TOK + n];
  out[n] = base[n] + wgt[2*n]*s0 + wgt[2*n+1]*s1;
}

extern "C" void kernel_launch(void* const* d_in, const int* in_sizes, int n_in,
                              void* d_out, int out_size, void* d_ws, size_t ws_size,
                              hipStream_t stream) {
  const float* x  = (const float*)d_in[0];
  const float* Wg = (const float*)d_in[1];
  const float* W1 = (const float*)d_in[2];
  const float* b1 = (const float*)d_in[3];
  const float* W2 = (const float*)d_in[4];
  const float* b2 = (const float*)d_in[5];
  const float* W3 = (const float*)d_in[6];
  const float* b3 = (const float*)d_in[7];
  float* out = (float*)d_out;

  char* ws = (char*)d_ws;
  size_t off = 0;
  auto alloc = [&](size_t bytes) -> char* {
    char* p = ws + off;
    off += (bytes + 255) & ~(size_t)255;
    return p;
  };
  unsigned short* xbf  = (unsigned short*)alloc((size_t)N_TOK * DDIM * 2);   // 48 MB
  unsigned short* w1bf = (unsigned short*)alloc((size_t)NCOLS * DDIM * 2);   // 9 MB
  float* v    = (float*)alloc((size_t)NCOLS * 4);
  float* cbuf = (float*)alloc(64);
  float* wgt  = (float*)alloc((size_t)N_TOK * 2 * 4);
  float* base = (float*)alloc((size_t)N_TOK * 4);
  float* part = (float*)alloc((size_t)NTILES * N_TOK * 4);                   // 6.3 MB
  if (off > ws_size) return;  // workspace too small — bail (will fail loudly in validation)

  cvt_kernel<<<(NCOLS*DDIM)/1024, 256, 0, stream>>>(W1, w1bf);
  vcalc_kernel<<<2*(FDIM/256), 256, 0, stream>>>(W2, W3, v);
  ccalc_kernel<<<1, 256, 0, stream>>>(b2, W3, b3, cbuf);
  gate_cvt_kernel<<<N_TOK/4, 256, 0, stream>>>(x, Wg, W3, cbuf, xbf, wgt, base);
  gemm_kernel<<<dim3(NTILES, N_TOK/128), 256, 0, stream>>>(xbf, w1bf, b1, v, part);
  final_kernel<<<N_TOK/256, 256, 0, stream>>>(part, wgt, base, out);
}

// Round 2
// 631.242 us; speedup vs baseline: 1.1011x; 1.1011x over previous
//
#include <hip/hip_runtime.h>
#include <hip/hip_bf16.h>
#include <stdint.h>

#define N_TOK 32768
#define DDIM  768
#define FDIM  3072
#define NCOLS (2*FDIM)      // 6144 rows of W1cat
#define BK    32
#define KTILES (DDIM/BK)    // 24
#define NTILES (NCOLS/128)  // 48 column tiles
#define VD_CHUNK 96         // vcalc d-chunk (768/8)

typedef __attribute__((ext_vector_type(8))) short bf16x8;
typedef __attribute__((ext_vector_type(4))) float f32x4;

__device__ __forceinline__ unsigned short f2bf(float f) {
  unsigned u = __builtin_bit_cast(unsigned, f);
  unsigned r = (u + 0x7fffu + ((u >> 16) & 1u)) >> 16;
  return (unsigned short)r;
}

__device__ __forceinline__ void gl_lds16(const void* g, void* l) {
  __builtin_amdgcn_global_load_lds(
      (const __attribute__((address_space(1))) unsigned int*)g,
      (__attribute__((address_space(3))) unsigned int*)l, 16, 0, 0);
}

// ---------- W1[:2] fp32 -> bf16 ----------
__global__ __launch_bounds__(256) void cvt_kernel(const float* __restrict__ src,
                                                  unsigned short* __restrict__ dst) {
  size_t i = ((size_t)blockIdx.x * 256 + threadIdx.x) * 4;
  float4 f = *(const float4*)(src + i);
  ushort4 u;
  u.x = f2bf(f.x); u.y = f2bf(f.y); u.z = f2bf(f.z); u.w = f2bf(f.w);
  *(ushort4*)(dst + i) = u;
}

// ---------- vpart[db][k*F+f] = sum_{d in chunk db} W2[k,d,f] * W3[k,0,d] ----------
// grid: (24, 8) = (k*12+fb, db) -> 192 blocks (was 24: latency-bound on 9% of CUs)
__global__ __launch_bounds__(256) void vcalc_kernel(const float* __restrict__ W2,
                                                    const float* __restrict__ W3,
                                                    float* __restrict__ vpart) {
  __shared__ float w3s[VD_CHUNK];
  int k  = blockIdx.x / 12;
  int fb = blockIdx.x % 12;
  int db = blockIdx.y;
  if (threadIdx.x < VD_CHUNK) w3s[threadIdx.x] = W3[k*DDIM + db*VD_CHUNK + threadIdx.x];
  __syncthreads();
  int f = fb*256 + threadIdx.x;
  const float* W2k = W2 + (size_t)k*DDIM*FDIM + (size_t)db*VD_CHUNK*FDIM + f;
  float s = 0.f;
  #pragma unroll 8
  for (int d = 0; d < VD_CHUNK; ++d) s += W2k[(size_t)d*FDIM] * w3s[d];
  vpart[(size_t)db*NCOLS + k*FDIM + f] = s;
}

// ---------- v = sum of 8 vpart chunks; block 0 also computes cbuf[k] ----------
__global__ __launch_bounds__(256) void vfinal_kernel(const float* __restrict__ vpart,
                                                     float* __restrict__ v,
                                                     const float* __restrict__ b2,
                                                     const float* __restrict__ W3,
                                                     const float* __restrict__ b3,
                                                     float* __restrict__ cbuf) {
  int f = blockIdx.x*256 + threadIdx.x;   // 24 blocks cover NCOLS
  float s = 0.f;
  #pragma unroll
  for (int db = 0; db < 8; ++db) s += vpart[(size_t)db*NCOLS + f];
  v[f] = s;
  if (blockIdx.x == 0 && threadIdx.x < 128) {
    int k = threadIdx.x >> 6, lane = threadIdx.x & 63;
    float c = 0.f;
    #pragma unroll
    for (int it = 0; it < DDIM/64; ++it) {
      int i = it*64 + lane;
      c += b2[k*DDIM + i] * W3[k*DDIM + i];
    }
    #pragma unroll
    for (int m = 1; m < 64; m <<= 1) c += __shfl_xor(c, m, 64);
    if (lane == 0) cbuf[k] = c + b3[k];
  }
}

// ---------- gate (softmax top-2 weights) + x->bf16 + W3 dots, one wave/row, float4 ----------
__global__ __launch_bounds__(256) void gate_cvt_kernel(
    const float* __restrict__ x, const float* __restrict__ Wg,
    const float* __restrict__ W3, const float* __restrict__ cbuf,
    unsigned short* __restrict__ xbf,
    float* __restrict__ wgt, float* __restrict__ base) {
  int wid  = threadIdx.x >> 6;
  int lane = threadIdx.x & 63;
  int n = blockIdx.x * 4 + wid;
  const float4* xr = (const float4*)(x + (size_t)n * DDIM);
  ushort4* xw = (ushort4*)(xbf + (size_t)n * DDIM);
  float acc[8] = {0,0,0,0,0,0,0,0};
  float d30 = 0.f, d31 = 0.f;
  #pragma unroll
  for (int it = 0; it < DDIM/256; ++it) {     // 3 iters of float4
    int i = it*64 + lane;
    float4 xv = xr[i];
    ushort4 u;
    u.x = f2bf(xv.x); u.y = f2bf(xv.y); u.z = f2bf(xv.z); u.w = f2bf(xv.w);
    xw[i] = u;
    #pragma unroll
    for (int e = 0; e < 8; ++e) {
      float4 w = ((const float4*)(Wg + e*DDIM))[i];
      acc[e] += xv.x*w.x + xv.y*w.y + xv.z*w.z + xv.w*w.w;
    }
    float4 wa = ((const float4*)W3)[i];
    d30 += xv.x*wa.x + xv.y*wa.y + xv.z*wa.z + xv.w*wa.w;
    float4 wb = ((const float4*)(W3 + DDIM))[i];
    d31 += xv.x*wb.x + xv.y*wb.y + xv.z*wb.z + xv.w*wb.w;
  }
  #pragma unroll
  for (int m = 1; m < 64; m <<= 1) {
    #pragma unroll
    for (int e = 0; e < 8; ++e) acc[e] += __shfl_xor(acc[e], m, 64);
    d30 += __shfl_xor(d30, m, 64);
    d31 += __shfl_xor(d31, m, 64);
  }
  if (lane == 0) {
    float l1 = acc[0]; int a1 = 0;
    #pragma unroll
    for (int e = 1; e < 8; ++e) if (acc[e] > l1) { l1 = acc[e]; a1 = e; }
    float l2 = -3.4e38f;
    #pragma unroll
    for (int e = 0; e < 8; ++e) if (e != a1 && acc[e] > l2) l2 = acc[e];
    float w0 = 1.f / (1.f + __expf(l2 - l1));   // top/(top+2nd); softmax Z cancels
    float w1 = 1.f - w0;
    wgt[2*n]   = w0;
    wgt[2*n+1] = w1;
    base[n] = w0 * (d30 + cbuf[0]) + w1 * (d31 + cbuf[1]);
  }
}

// ---------- fused GEMM: part[bn][row] = sum_{col in tile bn} relu(X@W1cat^T + b1)[row][col] * v[col] ----------
__global__ __launch_bounds__(256) void gemm_kernel(
    const unsigned short* __restrict__ A,   // 32768 x 768 bf16
    const unsigned short* __restrict__ B,   // 6144 x 768 bf16 (W1cat, B^T layout)
    const float* __restrict__ b1,           // 6144
    const float* __restrict__ v,            // 6144
    float* __restrict__ part) {             // 48 x 32768
  __shared__ __align__(16) unsigned short As[128*BK];
  __shared__ __align__(16) unsigned short Bs[128*BK];
  __shared__ float red[256];

  const int tid  = threadIdx.x;
  const int lane = tid & 63, wid = tid >> 6;
  const int wr = wid >> 1, wc = wid & 1;
  const int q  = lane >> 4, cl = lane & 15;
  const int bn = blockIdx.x;     // 0..47 col tile
  const int bm = blockIdx.y;     // 0..255 row tile

  // staging: thread t stages 16B slots t and t+256 (linear in LDS = global_load_lds order)
  // XOR swizzle: slot(r,kq) = r*4 + (kq ^ ((r>>1)&3))  -> 2-way bank aliasing (free)
  const int r0  = tid >> 2;
  const int kq0 = (tid & 3) ^ ((r0 >> 1) & 3);
  const int r1  = r0 + 64;
  const int kq1 = (tid & 3) ^ ((r1 >> 1) & 3);

  const unsigned short* Ab = A + (size_t)bm * 128 * DDIM;
  const unsigned short* Bb = B + (size_t)bn * 128 * DDIM;

  f32x4 zero = {0.f, 0.f, 0.f, 0.f};
  f32x4 acc[4][4];
  #pragma unroll
  for (int i = 0; i < 4; ++i)
    #pragma unroll
    for (int j = 0; j < 4; ++j) acc[i][j] = zero;

  int aoff[4], boff[4];
  #pragma unroll
  for (int i = 0; i < 4; ++i) {
    int ra = wr*64 + i*16 + cl;
    aoff[i] = (ra*4 + (q ^ ((ra>>1)&3))) * 16;
    int rb = wc*64 + i*16 + cl;
    boff[i] = (rb*4 + (q ^ ((rb>>1)&3))) * 16;
  }
  char* AsB = (char*)As;
  char* BsB = (char*)Bs;

  for (int kt = 0; kt < KTILES; ++kt) {
    int k0 = kt * BK;
    gl_lds16(Ab + (size_t)r0*DDIM + k0 + kq0*8, AsB + wid*1024);
    gl_lds16(Ab + (size_t)r1*DDIM + k0 + kq1*8, AsB + 4096 + wid*1024);
    gl_lds16(Bb + (size_t)r0*DDIM + k0 + kq0*8, BsB + wid*1024);
    gl_lds16(Bb + (size_t)r1*DDIM + k0 + kq1*8, BsB + 4096 + wid*1024);
    __syncthreads();
    bf16x8 af[4], bfr[4];
    #pragma unroll
    for (int i = 0; i < 4; ++i) {
      af[i]  = *(const bf16x8*)(AsB + aoff[i]);
      bfr[i] = *(const bf16x8*)(BsB + boff[i]);
    }
    #pragma unroll
    for (int i = 0; i < 4; ++i)
      #pragma unroll
      for (int j = 0; j < 4; ++j)
        acc[i][j] = __builtin_amdgcn_mfma_f32_16x16x32_bf16(af[i], bfr[j], acc[i][j], 0, 0, 0);
    __syncthreads();
  }

  // epilogue: relu(acc + b1[col]) * v[col], reduce over the tile's 128 cols per row
  float vv[4], bb[4];
  #pragma unroll
  for (int j = 0; j < 4; ++j) {
    int cg = bn*128 + wc*64 + j*16 + cl;
    vv[j] = v[cg];
    bb[j] = b1[cg];
  }
  // C/D layout: row = q*4 + reg, col = lane&15 (within each 16x16 tile)
  #pragma unroll
  for (int i = 0; i < 4; ++i) {
    #pragma unroll
    for (int r = 0; r < 4; ++r) {
      float s = 0.f;
      #pragma unroll
      for (int j = 0; j < 4; ++j) {
        float val = acc[i][j][r] + bb[j];
        val = fmaxf(val, 0.f);
        s += val * vv[j];
      }
      #pragma unroll
      for (int m = 1; m < 16; m <<= 1) s += __shfl_xor(s, m, 64);
      if (cl == 0) red[(wr*64 + i*16 + q*4 + r)*2 + wc] = s;
    }
  }
  __syncthreads();
  if (tid < 128)
    part[(size_t)bn * N_TOK + bm*128 + tid] = red[tid*2] + red[tid*2+1];
}

// ---------- final combine ----------
__global__ __launch_bounds__(256) void final_kernel(const float* __restrict__ part,
                                                    const float* __restrict__ wgt,
                                                    const float* __restrict__ base,
                                                    float* __restrict__ out) {
  int n = blockIdx.x * 256 + threadIdx.x;
  float s0 = 0.f, s1 = 0.f;
  #pragma unroll
  for (int t = 0; t < 24; ++t) s0 += part[(size_t)t*N_TOK + n];
  #pragma unroll
  for (int t = 24; t < 48; ++t) s1 += part[(size_t)t*N_TOK + n];
  out[n] = base[n] + wgt[2*n]*s0 + wgt[2*n+1]*s1;
}

extern "C" void kernel_launch(void* const* d_in, const int* in_sizes, int n_in,
                              void* d_out, int out_size, void* d_ws, size_t ws_size,
                              hipStream_t stream) {
  const float* x  = (const float*)d_in[0];
  const float* Wg = (const float*)d_in[1];
  const float* W1 = (const float*)d_in[2];
  const float* b1 = (const float*)d_in[3];
  const float* W2 = (const float*)d_in[4];
  const float* b2 = (const float*)d_in[5];
  const float* W3 = (const float*)d_in[6];
  const float* b3 = (const float*)d_in[7];
  float* out = (float*)d_out;

  char* ws = (char*)d_ws;
  size_t off = 0;
  auto alloc = [&](size_t bytes) -> char* {
    char* p = ws + off;
    off += (bytes + 255) & ~(size_t)255;
    return p;
  };
  unsigned short* xbf  = (unsigned short*)alloc((size_t)N_TOK * DDIM * 2);   // 48 MB
  unsigned short* w1bf = (unsigned short*)alloc((size_t)NCOLS * DDIM * 2);   // 9 MB
  float* vpart = (float*)alloc((size_t)8 * NCOLS * 4);
  float* v     = (float*)alloc((size_t)NCOLS * 4);
  float* cbuf  = (float*)alloc(64);
  float* wgt   = (float*)alloc((size_t)N_TOK * 2 * 4);
  float* base  = (float*)alloc((size_t)N_TOK * 4);
  float* part  = (float*)alloc((size_t)NTILES * N_TOK * 4);                  // 6.3 MB
  if (off > ws_size) return;

  cvt_kernel<<<(NCOLS*DDIM)/1024, 256, 0, stream>>>(W1, w1bf);
  vcalc_kernel<<<dim3(24, 8), 256, 0, stream>>>(W2, W3, vpart);
  vfinal_kernel<<<NCOLS/256, 256, 0, stream>>>(vpart, v, b2, W3, b3, cbuf);
  gate_cvt_kernel<<<N_TOK/4, 256, 0, stream>>>(x, Wg, W3, cbuf, xbf, wgt, base);
  gemm_kernel<<<dim3(NTILES, N_TOK/128), 256, 0, stream>>>(xbf, w1bf, b1, v, part);
  final_kernel<<<N_TOK/256, 256, 0, stream>>>(part, wgt, base, out);
}